// Round 10
// baseline (99.211 us; speedup 1.0000x reference)
//
#include <hip/hip_runtime.h>
#include <hip/hip_bf16.h>
#include <math.h>

#define S_DIM 2048
#define B_DIM 64
#define H_DIM 1024
#define HC     64                   // h-columns per v-block (one per lane)
#define BLK_B  4                    // b's per v-block
#define S_PIN  1024                 // s < S_PIN: plain loads (L3-pinned 256 MB half)

typedef float f32x4 __attribute__((ext_vector_type(4)));

// ---------------------------------------------------------------------------
// Kernel 1: v[b,h] = sum_k hidden[b,k] * W[k,h]  — h-SPLIT, single kernel.
// (unchanged from round 9 — measured good)
// ---------------------------------------------------------------------------
__global__ __launch_bounds__(512) void v_kernel(
    const float* __restrict__ hidden,   // [B,H]
    const float* __restrict__ W,        // [H,H]
    float* __restrict__ v)              // [B,H]
{
    const int h0   = blockIdx.x * HC;
    const int b0   = blockIdx.y * BLK_B;
    const int tid  = threadIdx.x;
    const int wave = tid >> 6;          // 0..7
    const int lane = tid & 63;
    const int h    = h0 + lane;

    __shared__ float s_hidT[H_DIM][BLK_B];   // transposed: [k][bb], 16 KB
    {
        const int i  = tid * 8;
        const int bb = i >> 10;              // i / H_DIM
        const int kk = i & (H_DIM - 1);
        const f32x4 lo = *reinterpret_cast<const f32x4*>(hidden + (size_t)(b0 + bb) * H_DIM + kk);
        const f32x4 hi = *reinterpret_cast<const f32x4*>(hidden + (size_t)(b0 + bb) * H_DIM + kk + 4);
        s_hidT[kk + 0][bb] = lo.x; s_hidT[kk + 1][bb] = lo.y;
        s_hidT[kk + 2][bb] = lo.z; s_hidT[kk + 3][bb] = lo.w;
        s_hidT[kk + 4][bb] = hi.x; s_hidT[kk + 5][bb] = hi.y;
        s_hidT[kk + 6][bb] = hi.z; s_hidT[kk + 7][bb] = hi.w;
    }
    __syncthreads();

    const int k0 = wave * (H_DIM / 8);       // 128-k chunk per wave
    f32x4 acc = (f32x4)0.f;
#pragma unroll 8
    for (int k = 0; k < H_DIM / 8; ++k) {
        const float w  = W[(size_t)(k0 + k) * H_DIM + h];
        const f32x4 hv = *reinterpret_cast<const f32x4*>(&s_hidT[k0 + k][0]);
        acc.x = fmaf(hv.x, w, acc.x);
        acc.y = fmaf(hv.y, w, acc.y);
        acc.z = fmaf(hv.z, w, acc.z);
        acc.w = fmaf(hv.w, w, acc.w);
    }

    __shared__ float red[8][BLK_B][HC];      // 8 KB
    red[wave][0][lane] = acc.x;
    red[wave][1][lane] = acc.y;
    red[wave][2][lane] = acc.z;
    red[wave][3][lane] = acc.w;
    __syncthreads();

    if (tid < BLK_B * HC) {
        const int bb = tid >> 6;
        const int l  = tid & 63;
        float s = 0.f;
#pragma unroll
        for (int w2 = 0; w2 < 8; ++w2) s += red[w2][bb][l];
        v[(size_t)(b0 + bb) * H_DIM + h0 + l] = s;
    }
}

// ---------------------------------------------------------------------------
// Kernel 2: scores[b,s] = dot(v[b,:], enc[s,b,:])
// L3-PINNING SPLIT: s < S_PIN uses PLAIN loads -> those 256 MB allocate
// normally and stay resident in the 256 MB Infinity Cache across graph
// replays; s >= S_PIN uses NT (evict-first) loads so the streamed half never
// displaces the pinned half. Steady state: half from L3, half from HBM,
// concurrently. (Round-4 FETCH=263MB proved ~L3-capacity retention of enc.)
// NO fences, NO semaphores (round-4 lesson: device-scope coherence = 7x).
// ---------------------------------------------------------------------------
template<bool NT>
__device__ __forceinline__ f32x4 ld4(const float* p) {
    if constexpr (NT)
        return __builtin_nontemporal_load(reinterpret_cast<const f32x4*>(p));
    else
        return *reinterpret_cast<const f32x4*>(p);
}

template<bool NT>
__device__ __forceinline__ void scores_body(
    const float* __restrict__ enc, const float* __restrict__ v,
    float* __restrict__ scores, int b, int s_base0)
{
    const int wave   = threadIdx.x >> 6;
    const int lane   = threadIdx.x & 63;
    const int s_base = s_base0 + wave * 16;

    const float* vb = v + (size_t)b * H_DIM;
    const int o = lane * 4;
    const f32x4 v0 = *reinterpret_cast<const f32x4*>(vb + o);
    const f32x4 v1 = *reinterpret_cast<const f32x4*>(vb + o + 256);
    const f32x4 v2 = *reinterpret_cast<const f32x4*>(vb + o + 512);
    const f32x4 v3 = *reinterpret_cast<const f32x4*>(vb + o + 768);

    const size_t srow = (size_t)B_DIM * H_DIM;

    for (int i = 0; i < 16; i += 4) {
        const float* ra = enc + ((size_t)(s_base + i) * B_DIM + b) * H_DIM;
        const float* rb = ra + srow;
        const float* rc = rb + srow;
        const float* rd = rc + srow;

        const f32x4 a0 = ld4<NT>(ra + o);
        const f32x4 a1 = ld4<NT>(ra + o + 256);
        const f32x4 a2 = ld4<NT>(ra + o + 512);
        const f32x4 a3 = ld4<NT>(ra + o + 768);
        const f32x4 b0 = ld4<NT>(rb + o);
        const f32x4 b1 = ld4<NT>(rb + o + 256);
        const f32x4 b2 = ld4<NT>(rb + o + 512);
        const f32x4 b3 = ld4<NT>(rb + o + 768);
        const f32x4 c0 = ld4<NT>(rc + o);
        const f32x4 c1 = ld4<NT>(rc + o + 256);
        const f32x4 c2 = ld4<NT>(rc + o + 512);
        const f32x4 c3 = ld4<NT>(rc + o + 768);
        const f32x4 d0 = ld4<NT>(rd + o);
        const f32x4 d1 = ld4<NT>(rd + o + 256);
        const f32x4 d2 = ld4<NT>(rd + o + 512);
        const f32x4 d3 = ld4<NT>(rd + o + 768);

        float acc_a = v0.x * a0.x + v0.y * a0.y + v0.z * a0.z + v0.w * a0.w
                    + v1.x * a1.x + v1.y * a1.y + v1.z * a1.z + v1.w * a1.w
                    + v2.x * a2.x + v2.y * a2.y + v2.z * a2.z + v2.w * a2.w
                    + v3.x * a3.x + v3.y * a3.y + v3.z * a3.z + v3.w * a3.w;
        float acc_b = v0.x * b0.x + v0.y * b0.y + v0.z * b0.z + v0.w * b0.w
                    + v1.x * b1.x + v1.y * b1.y + v1.z * b1.z + v1.w * b1.w
                    + v2.x * b2.x + v2.y * b2.y + v2.z * b2.z + v2.w * b2.w
                    + v3.x * b3.x + v3.y * b3.y + v3.z * b3.z + v3.w * b3.w;
        float acc_c = v0.x * c0.x + v0.y * c0.y + v0.z * c0.z + v0.w * c0.w
                    + v1.x * c1.x + v1.y * c1.y + v1.z * c1.z + v1.w * c1.w
                    + v2.x * c2.x + v2.y * c2.y + v2.z * c2.z + v2.w * c2.w
                    + v3.x * c3.x + v3.y * c3.y + v3.z * c3.z + v3.w * c3.w;
        float acc_d = v0.x * d0.x + v0.y * d0.y + v0.z * d0.z + v0.w * d0.w
                    + v1.x * d1.x + v1.y * d1.y + v1.z * d1.z + v1.w * d1.w
                    + v2.x * d2.x + v2.y * d2.y + v2.z * d2.z + v2.w * d2.w
                    + v3.x * d3.x + v3.y * d3.y + v3.z * d3.z + v3.w * d3.w;

#pragma unroll
        for (int off = 32; off > 0; off >>= 1) {
            acc_a += __shfl_xor(acc_a, off);
            acc_b += __shfl_xor(acc_b, off);
            acc_c += __shfl_xor(acc_c, off);
            acc_d += __shfl_xor(acc_d, off);
        }

        if (lane == 0) {
            f32x4 r; r.x = acc_a; r.y = acc_b; r.z = acc_c; r.w = acc_d;
            *reinterpret_cast<f32x4*>(scores + (size_t)b * S_DIM + s_base + i) = r;
        }
    }
}

__global__ __launch_bounds__(256) void scores_kernel(
    const float* __restrict__ enc,      // [S,B,H]
    const float* __restrict__ v,        // [B,H]
    float* __restrict__ scores)         // [B,S]
{
    const int b       = blockIdx.y;
    const int s_base0 = blockIdx.x * 64;

    if (s_base0 < S_PIN)
        scores_body<false>(enc, v, scores, b, s_base0);  // pinned half: plain
    else
        scores_body<true>(enc, v, scores, b, s_base0);   // streamed half: nt
}

// ---------------------------------------------------------------------------
// Kernel 3: out[b,0,s] = softmax over s of scores[b,:]
// (unchanged from round 9 — measured good)
// ---------------------------------------------------------------------------
__global__ __launch_bounds__(256) void softmax_kernel(
    const float* __restrict__ scores,   // [B,S]
    float* __restrict__ out)            // [B,1,S]
{
    const int b   = blockIdx.x;
    const int tid = threadIdx.x;
    const float* row = scores + (size_t)b * S_DIM;

    f32x4 va = *reinterpret_cast<const f32x4*>(row + tid * 8);
    f32x4 vb = *reinterpret_cast<const f32x4*>(row + tid * 8 + 4);

    float m = fmaxf(fmaxf(fmaxf(va.x, va.y), fmaxf(va.z, va.w)),
                    fmaxf(fmaxf(vb.x, vb.y), fmaxf(vb.z, vb.w)));

    __shared__ float red[256];
    red[tid] = m;
    __syncthreads();
    for (int off = 128; off > 0; off >>= 1) {
        if (tid < off) red[tid] = fmaxf(red[tid], red[tid + off]);
        __syncthreads();
    }
    m = red[0];
    __syncthreads();

    va.x = __expf(va.x - m); va.y = __expf(va.y - m);
    va.z = __expf(va.z - m); va.w = __expf(va.w - m);
    vb.x = __expf(vb.x - m); vb.y = __expf(vb.y - m);
    vb.z = __expf(vb.z - m); vb.w = __expf(vb.w - m);
    const float sum = va.x + va.y + va.z + va.w + vb.x + vb.y + vb.z + vb.w;

    red[tid] = sum;
    __syncthreads();
    for (int off = 128; off > 0; off >>= 1) {
        if (tid < off) red[tid] += red[tid + off];
        __syncthreads();
    }
    const float inv = 1.0f / red[0];
    __syncthreads();

    va *= inv;
    vb *= inv;
    *reinterpret_cast<f32x4*>(out + (size_t)b * S_DIM + tid * 8)     = va;
    *reinterpret_cast<f32x4*>(out + (size_t)b * S_DIM + tid * 8 + 4) = vb;
}

// ---------------------------------------------------------------------------
extern "C" void kernel_launch(void* const* d_in, const int* in_sizes, int n_in,
                              void* d_out, int out_size, void* d_ws, size_t ws_size,
                              hipStream_t stream) {
    const float* hidden = (const float*)d_in[0];   // [1,B,H]
    const float* enc    = (const float*)d_in[1];   // [S,B,H]
    const float* W      = (const float*)d_in[2];   // [H,H]
    // d_in[3] = bias: unused — constant per-row shift cancels in softmax.
    float* out          = (float*)d_out;           // [B,1,S]

    float* ws     = (float*)d_ws;
    float* v      = ws;                                 // B*H (256 KB)
    float* scores = v + (size_t)B_DIM * H_DIM;          // B*S (512 KB)

    v_kernel<<<dim3(H_DIM / HC, B_DIM / BLK_B), dim3(512), 0, stream>>>(hidden, W, v);
    scores_kernel<<<dim3(S_DIM / 64, B_DIM), dim3(256), 0, stream>>>(enc, v, scores);
    softmax_kernel<<<dim3(B_DIM), dim3(256), 0, stream>>>(scores, out);
}

// Round 11
// 97.910 us; speedup vs baseline: 1.0133x; 1.0133x over previous
//
#include <hip/hip_runtime.h>
#include <hip/hip_bf16.h>
#include <math.h>

#define S_DIM 2048
#define B_DIM 64
#define H_DIM 1024
#define HC     64                   // h-columns per v-block (one per lane)
#define BLK_B  4                    // b's per v-block

typedef float f32x4 __attribute__((ext_vector_type(4)));

// ---------------------------------------------------------------------------
// Kernel 1: v[b,h] = sum_k hidden[b,k] * W[k,h]  — h-SPLIT, single kernel.
// Grid (H/HC, B/BLK_B) = (16,16) = 256 blocks x 512 threads (1 block/CU).
// Each block owns 64 columns x 4 b's and the FULL k range -> no cross-block
// reduction. W traffic 64 MB, L2/L3-resident on replay. 8 waves each own a
// k-eighth; lane l owns column h0+l -> per iter one coalesced 256 B W load +
// broadcast ds_read_b128 of transposed hidden + 4 FMA. LDS reduce over waves.
// Bias dropped everywhere: constant shift per row b cancels in softmax.
// ---------------------------------------------------------------------------
__global__ __launch_bounds__(512) void v_kernel(
    const float* __restrict__ hidden,   // [B,H]
    const float* __restrict__ W,        // [H,H]
    float* __restrict__ v)              // [B,H]
{
    const int h0   = blockIdx.x * HC;
    const int b0   = blockIdx.y * BLK_B;
    const int tid  = threadIdx.x;
    const int wave = tid >> 6;          // 0..7
    const int lane = tid & 63;
    const int h    = h0 + lane;

    __shared__ float s_hidT[H_DIM][BLK_B];   // transposed: [k][bb], 16 KB
    {
        const int i  = tid * 8;
        const int bb = i >> 10;              // i / H_DIM
        const int kk = i & (H_DIM - 1);
        const f32x4 lo = *reinterpret_cast<const f32x4*>(hidden + (size_t)(b0 + bb) * H_DIM + kk);
        const f32x4 hi = *reinterpret_cast<const f32x4*>(hidden + (size_t)(b0 + bb) * H_DIM + kk + 4);
        s_hidT[kk + 0][bb] = lo.x; s_hidT[kk + 1][bb] = lo.y;
        s_hidT[kk + 2][bb] = lo.z; s_hidT[kk + 3][bb] = lo.w;
        s_hidT[kk + 4][bb] = hi.x; s_hidT[kk + 5][bb] = hi.y;
        s_hidT[kk + 6][bb] = hi.z; s_hidT[kk + 7][bb] = hi.w;
    }
    __syncthreads();

    const int k0 = wave * (H_DIM / 8);       // 128-k chunk per wave
    f32x4 acc = (f32x4)0.f;                  // acc[bb] for this lane's column
#pragma unroll 8
    for (int k = 0; k < H_DIM / 8; ++k) {
        const float w  = W[(size_t)(k0 + k) * H_DIM + h];          // 256B/wave coalesced
        const f32x4 hv = *reinterpret_cast<const f32x4*>(&s_hidT[k0 + k][0]); // broadcast
        acc.x = fmaf(hv.x, w, acc.x);
        acc.y = fmaf(hv.y, w, acc.y);
        acc.z = fmaf(hv.z, w, acc.z);
        acc.w = fmaf(hv.w, w, acc.w);
    }

    __shared__ float red[8][BLK_B][HC];      // 8 KB
    red[wave][0][lane] = acc.x;
    red[wave][1][lane] = acc.y;
    red[wave][2][lane] = acc.z;
    red[wave][3][lane] = acc.w;
    __syncthreads();

    if (tid < BLK_B * HC) {                  // 256 threads finalize
        const int bb = tid >> 6;
        const int l  = tid & 63;
        float s = 0.f;
#pragma unroll
        for (int w2 = 0; w2 < 8; ++w2) s += red[w2][bb][l];
        v[(size_t)(b0 + bb) * H_DIM + h0 + l] = s;
    }
}

// ---------------------------------------------------------------------------
// Kernel 2: scores[b,s] = dot(v[b,:], enc[s,b,:])
// Grid (S/64, B) = (32,64), 256 threads = 4 waves, 16 s per wave in batches
// of 4 (16 x 16B nt loads in flight, 4 independent acc chains).
// NT loads on enc are REQUIRED: round-7 measured removing them = +24.5 µs
// (plain loads thrash L2; nt protects L2). L3-pin split tested round-10:
// neutral-negative — do not reintroduce.
// NO fences, NO semaphores (round-4 lesson: device-scope coherence = 7x).
// ---------------------------------------------------------------------------
__global__ __launch_bounds__(256) void scores_kernel(
    const float* __restrict__ enc,      // [S,B,H]
    const float* __restrict__ v,        // [B,H]
    float* __restrict__ scores)         // [B,S]
{
    const int b      = blockIdx.y;
    const int wave   = threadIdx.x >> 6;
    const int lane   = threadIdx.x & 63;
    const int s_base = blockIdx.x * 64 + wave * 16;

    const float* vb = v + (size_t)b * H_DIM;
    const int o = lane * 4;
    const f32x4 v0 = *reinterpret_cast<const f32x4*>(vb + o);
    const f32x4 v1 = *reinterpret_cast<const f32x4*>(vb + o + 256);
    const f32x4 v2 = *reinterpret_cast<const f32x4*>(vb + o + 512);
    const f32x4 v3 = *reinterpret_cast<const f32x4*>(vb + o + 768);

    const size_t srow = (size_t)B_DIM * H_DIM;   // stride between s rows

    for (int i = 0; i < 16; i += 4) {
        const float* ra = enc + ((size_t)(s_base + i) * B_DIM + b) * H_DIM;
        const float* rb = ra + srow;
        const float* rc = rb + srow;
        const float* rd = rc + srow;

        const f32x4 a0 = __builtin_nontemporal_load(reinterpret_cast<const f32x4*>(ra + o));
        const f32x4 a1 = __builtin_nontemporal_load(reinterpret_cast<const f32x4*>(ra + o + 256));
        const f32x4 a2 = __builtin_nontemporal_load(reinterpret_cast<const f32x4*>(ra + o + 512));
        const f32x4 a3 = __builtin_nontemporal_load(reinterpret_cast<const f32x4*>(ra + o + 768));
        const f32x4 b0 = __builtin_nontemporal_load(reinterpret_cast<const f32x4*>(rb + o));
        const f32x4 b1 = __builtin_nontemporal_load(reinterpret_cast<const f32x4*>(rb + o + 256));
        const f32x4 b2 = __builtin_nontemporal_load(reinterpret_cast<const f32x4*>(rb + o + 512));
        const f32x4 b3 = __builtin_nontemporal_load(reinterpret_cast<const f32x4*>(rb + o + 768));
        const f32x4 c0 = __builtin_nontemporal_load(reinterpret_cast<const f32x4*>(rc + o));
        const f32x4 c1 = __builtin_nontemporal_load(reinterpret_cast<const f32x4*>(rc + o + 256));
        const f32x4 c2 = __builtin_nontemporal_load(reinterpret_cast<const f32x4*>(rc + o + 512));
        const f32x4 c3 = __builtin_nontemporal_load(reinterpret_cast<const f32x4*>(rc + o + 768));
        const f32x4 d0 = __builtin_nontemporal_load(reinterpret_cast<const f32x4*>(rd + o));
        const f32x4 d1 = __builtin_nontemporal_load(reinterpret_cast<const f32x4*>(rd + o + 256));
        const f32x4 d2 = __builtin_nontemporal_load(reinterpret_cast<const f32x4*>(rd + o + 512));
        const f32x4 d3 = __builtin_nontemporal_load(reinterpret_cast<const f32x4*>(rd + o + 768));

        float acc_a = v0.x * a0.x + v0.y * a0.y + v0.z * a0.z + v0.w * a0.w
                    + v1.x * a1.x + v1.y * a1.y + v1.z * a1.z + v1.w * a1.w
                    + v2.x * a2.x + v2.y * a2.y + v2.z * a2.z + v2.w * a2.w
                    + v3.x * a3.x + v3.y * a3.y + v3.z * a3.z + v3.w * a3.w;
        float acc_b = v0.x * b0.x + v0.y * b0.y + v0.z * b0.z + v0.w * b0.w
                    + v1.x * b1.x + v1.y * b1.y + v1.z * b1.z + v1.w * b1.w
                    + v2.x * b2.x + v2.y * b2.y + v2.z * b2.z + v2.w * b2.w
                    + v3.x * b3.x + v3.y * b3.y + v3.z * b3.z + v3.w * b3.w;
        float acc_c = v0.x * c0.x + v0.y * c0.y + v0.z * c0.z + v0.w * c0.w
                    + v1.x * c1.x + v1.y * c1.y + v1.z * c1.z + v1.w * c1.w
                    + v2.x * c2.x + v2.y * c2.y + v2.z * c2.z + v2.w * c2.w
                    + v3.x * c3.x + v3.y * c3.y + v3.z * c3.z + v3.w * c3.w;
        float acc_d = v0.x * d0.x + v0.y * d0.y + v0.z * d0.z + v0.w * d0.w
                    + v1.x * d1.x + v1.y * d1.y + v1.z * d1.z + v1.w * d1.w
                    + v2.x * d2.x + v2.y * d2.y + v2.z * d2.z + v2.w * d2.w
                    + v3.x * d3.x + v3.y * d3.y + v3.z * d3.z + v3.w * d3.w;

#pragma unroll
        for (int off = 32; off > 0; off >>= 1) {
            acc_a += __shfl_xor(acc_a, off);
            acc_b += __shfl_xor(acc_b, off);
            acc_c += __shfl_xor(acc_c, off);
            acc_d += __shfl_xor(acc_d, off);
        }

        if (lane == 0) {
            f32x4 r; r.x = acc_a; r.y = acc_b; r.z = acc_c; r.w = acc_d;
            *reinterpret_cast<f32x4*>(scores + (size_t)b * S_DIM + s_base + i) = r;
        }
    }
}

// ---------------------------------------------------------------------------
// Kernel 3: out[b,0,s] = softmax over s of scores[b,:]
// One block per b; f32x4 vectorized row access (8 floats/thread).
// ---------------------------------------------------------------------------
__global__ __launch_bounds__(256) void softmax_kernel(
    const float* __restrict__ scores,   // [B,S]
    float* __restrict__ out)            // [B,1,S]
{
    const int b   = blockIdx.x;
    const int tid = threadIdx.x;
    const float* row = scores + (size_t)b * S_DIM;

    f32x4 va = *reinterpret_cast<const f32x4*>(row + tid * 8);
    f32x4 vb = *reinterpret_cast<const f32x4*>(row + tid * 8 + 4);

    float m = fmaxf(fmaxf(fmaxf(va.x, va.y), fmaxf(va.z, va.w)),
                    fmaxf(fmaxf(vb.x, vb.y), fmaxf(vb.z, vb.w)));

    __shared__ float red[256];
    red[tid] = m;
    __syncthreads();
    for (int off = 128; off > 0; off >>= 1) {
        if (tid < off) red[tid] = fmaxf(red[tid], red[tid + off]);
        __syncthreads();
    }
    m = red[0];
    __syncthreads();

    va.x = __expf(va.x - m); va.y = __expf(va.y - m);
    va.z = __expf(va.z - m); va.w = __expf(va.w - m);
    vb.x = __expf(vb.x - m); vb.y = __expf(vb.y - m);
    vb.z = __expf(vb.z - m); vb.w = __expf(vb.w - m);
    const float sum = va.x + va.y + va.z + va.w + vb.x + vb.y + vb.z + vb.w;

    red[tid] = sum;
    __syncthreads();
    for (int off = 128; off > 0; off >>= 1) {
        if (tid < off) red[tid] += red[tid + off];
        __syncthreads();
    }
    const float inv = 1.0f / red[0];
    __syncthreads();

    va *= inv;
    vb *= inv;
    *reinterpret_cast<f32x4*>(out + (size_t)b * S_DIM + tid * 8)     = va;
    *reinterpret_cast<f32x4*>(out + (size_t)b * S_DIM + tid * 8 + 4) = vb;
}

// ---------------------------------------------------------------------------
extern "C" void kernel_launch(void* const* d_in, const int* in_sizes, int n_in,
                              void* d_out, int out_size, void* d_ws, size_t ws_size,
                              hipStream_t stream) {
    const float* hidden = (const float*)d_in[0];   // [1,B,H]
    const float* enc    = (const float*)d_in[1];   // [S,B,H]
    const float* W      = (const float*)d_in[2];   // [H,H]
    // d_in[3] = bias: unused — constant per-row shift cancels in softmax.
    float* out          = (float*)d_out;           // [B,1,S]

    float* ws     = (float*)d_ws;
    float* v      = ws;                                 // B*H (256 KB)
    float* scores = v + (size_t)B_DIM * H_DIM;          // B*S (512 KB)

    v_kernel<<<dim3(H_DIM / HC, B_DIM / BLK_B), dim3(512), 0, stream>>>(hidden, W, v);
    scores_kernel<<<dim3(S_DIM / 64, B_DIM), dim3(256), 0, stream>>>(enc, v, scores);
    softmax_kernel<<<dim3(B_DIM), dim3(256), 0, stream>>>(scores, out);
}